// Round 17
// baseline (1252.605 us; speedup 1.0000x reference)
//
#include <hip/hip_runtime.h>
#include <math.h>

#define NPTS 4096
#define KNN 16
#define LN_EPS 1e-5f

// ---------------------------------------------------------------------------
// MODEL R (r16 conclusion): np ref = numpy rewrite using BLAS matmul for the
// gram term. d2 arithmetic:
//   sq  = (x*x + y*y) + z*z        sequential ufuncs, NO fma
//   dot = fma(z,z', fma(y,y', x*x'))   BLAS sgemm K=3 rank-1-update order
//   d2  = (sq_n + sq_m) - (2*dot)  separate ufuncs, each rounded
// Selection: stable top_k (lower j at equal keys).
// Dot-form d2 lives on a ~2^-23 cancellation grid; the FMA-vs-sequential dot
// crumb shifts d2 by one grid step at a handful of queries — including the
// boundary-flip B that none of the sequential/diff/exact variants matched.
// Tested with the DUMB (known-faithful) pipeline for the first time (the
// r4 "test" of this arithmetic ran through the buggy clever pipeline).
// ---------------------------------------------------------------------------

__global__ __launch_bounds__(256) void proj3_kernel(
    const float* __restrict__ x, const float* __restrict__ Wq,
    const float* __restrict__ Wk, const float* __restrict__ Wv,
    float* __restrict__ qf, float* __restrict__ kf, float* __restrict__ vf) {
  int g = blockIdx.x * 256 + threadIdx.x;
  int r = g >> 6, c = g & 63;
  float sq = 0.f, sk = 0.f, sv = 0.f;
  for (int i = 0; i < 64; ++i) {
    float xv = x[r*64 + i];
    sq += xv * Wq[i*64 + c];
    sk += xv * Wk[i*64 + c];
    sv += xv * Wv[i*64 + c];
  }
  qf[g] = sq; kf[g] = sk; vf[g] = sv;
}

// ---------------------------------------------------------------------------
// KNN: V1 arithmetic (BLAS-style FMA dot, sequential sq, unfused combine),
// one thread per query, sorted top-16, strict < insert (stable lower-j).
// ---------------------------------------------------------------------------
__global__ __launch_bounds__(64) void knn_blas_kernel(
    const float* __restrict__ pos, int* __restrict__ idx_out) {
  __shared__ float s_x[NPTS], s_y[NPTS], s_z[NPTS], s_sq[NPTS];
  int tid = threadIdx.x, b = blockIdx.y;
  const float* pb = pos + b*NPTS*3;
  for (int j = tid; j < NPTS; j += 64) {
    float px = pb[j*3+0], py = pb[j*3+1], pz = pb[j*3+2];
    s_x[j] = px; s_y[j] = py; s_z[j] = pz;
    s_sq[j] = __fadd_rn(__fadd_rn(__fmul_rn(px,px), __fmul_rn(py,py)),
                        __fmul_rn(pz,pz));
  }
  __syncthreads();
  int n = blockIdx.x * 64 + tid;
  float qx = s_x[n], qy = s_y[n], qz = s_z[n], sqn = s_sq[n];
  float ld[16]; int lj[16];
#pragma unroll
  for (int u = 0; u < 16; ++u) { ld[u] = INFINITY; lj[u] = 0x7fffffff; }
  for (int j = 0; j < NPTS; ++j) {
    // BLAS sgemm K=3 rank-1 update order: k=0 mul, then fma k=1, fma k=2.
    float acc = __fmul_rn(qx, s_x[j]);
    acc = __fmaf_rn(qy, s_y[j], acc);
    acc = __fmaf_rn(qz, s_z[j], acc);
    float d2 = __fsub_rn(__fadd_rn(sqn, s_sq[j]), __fmul_rn(2.0f, acc));
    if (d2 < ld[15]) {
      float dd = d2; int jj = j;
#pragma unroll
      for (int u = 0; u < 16; ++u) {
        bool sw = dd < ld[u];
        float nd = sw ? dd : ld[u]; float td = sw ? ld[u] : dd;
        int   nj = sw ? jj : lj[u]; int   tj = sw ? lj[u] : jj;
        ld[u] = nd; lj[u] = nj; dd = td; jj = tj;
      }
    }
  }
  int* outp = idx_out + (b*NPTS + n)*KNN;
#pragma unroll
  for (int u = 0; u < 16; ++u) outp[u] = b*NPTS + lj[u];   // GLOBAL row index
}

// ---------------------------------------------------------------------------
// Fused layer, direct transcription (r5 verbatim, known-good).
// ---------------------------------------------------------------------------
__global__ __launch_bounds__(256) void fuse_dumb_kernel(
    const float* __restrict__ pos, const int* __restrict__ idx,
    const float* __restrict__ qf, const float* __restrict__ kf,
    const float* __restrict__ vf,
    const float* __restrict__ p_w1, const float* __restrict__ p_b1,
    const float* __restrict__ p_g, const float* __restrict__ p_be,
    const float* __restrict__ p_w2, const float* __restrict__ p_b2,
    const float* __restrict__ a_w1, const float* __restrict__ a_b1,
    const float* __restrict__ a_g, const float* __restrict__ a_be,
    const float* __restrict__ a_w2, const float* __restrict__ a_b2,
    float* __restrict__ out) {
  __shared__ int   s_j[16];
  __shared__ float s_h[16][12];
  __shared__ float s_win[16][64];
  __shared__ float s_ve[16][64];
  __shared__ float s_ai[16][64];
  __shared__ float s_act[16][64];
  __shared__ float s_t2[16][64];
  __shared__ float s_m[16], s_rs[16];

  int tid = threadIdx.x;
  int p = blockIdx.x;

  if (tid < 16) {
    int j = idx[p*KNN + tid];
    s_j[tid] = j;
    float rx = pos[p*3+0] - pos[j*3+0];
    float ry = pos[p*3+1] - pos[j*3+1];
    float rz = pos[p*3+2] - pos[j*3+2];
    float hv[12];
    float mean = 0.f;
#pragma unroll
    for (int h = 0; h < 12; ++h) {
      float v = rx*p_w1[h] + ry*p_w1[12+h] + rz*p_w1[24+h] + p_b1[h];
      hv[h] = v; mean += v;
    }
    mean *= (1.0f/12.0f);
    float var = 0.f;
#pragma unroll
    for (int h = 0; h < 12; ++h) { float d = hv[h] - mean; var += d*d; }
    var *= (1.0f/12.0f);
    float rs = rsqrtf(var + LN_EPS);
#pragma unroll
    for (int h = 0; h < 12; ++h) {
      float a = (hv[h] - mean)*rs*p_g[h] + p_be[h];
      s_h[tid][h] = fmaxf(a, 0.f);
    }
  }
  __syncthreads();

  int c = tid & 63, kq = tid >> 6;

  {
    float qv = qf[p*64 + c];
#pragma unroll
    for (int it = 0; it < 4; ++it) {
      int k = it*4 + kq;
      int j = s_j[k];
      float pe = p_b2[c];
#pragma unroll
      for (int h = 0; h < 12; ++h) pe += s_h[k][h] * p_w2[h*64 + c];
      s_win[k][c] = qv - kf[j*64 + c] + pe;
      s_ve[k][c]  = vf[j*64 + c] + pe;
    }
  }
  __syncthreads();

#pragma unroll
  for (int it = 0; it < 4; ++it) {
    int k = it*4 + kq;
    float s = a_b1[c];
    for (int i = 0; i < 64; ++i) s += s_win[k][i] * a_w1[i*64 + c];
    s_ai[k][c] = s;
  }
  __syncthreads();

  if (tid < 16) {
    float m = 0.f;
    for (int c2 = 0; c2 < 64; ++c2) m += s_ai[tid][c2];
    m *= (1.0f/64.0f);
    float v = 0.f;
    for (int c2 = 0; c2 < 64; ++c2) { float d = s_ai[tid][c2] - m; v += d*d; }
    v *= (1.0f/64.0f);
    s_m[tid] = m; s_rs[tid] = rsqrtf(v + LN_EPS);
  }
  __syncthreads();
#pragma unroll
  for (int it = 0; it < 4; ++it) {
    int k = it*4 + kq;
    s_act[k][c] = fmaxf((s_ai[k][c] - s_m[k])*s_rs[k]*a_g[c] + a_be[c], 0.f);
  }
  __syncthreads();

#pragma unroll
  for (int it = 0; it < 4; ++it) {
    int k = it*4 + kq;
    float s = a_b2[c];
    for (int i = 0; i < 64; ++i) s += s_act[k][i] * a_w2[i*64 + c];
    s_t2[k][c] = s;
  }
  __syncthreads();

  if (tid < 64) {
    float mx = -INFINITY;
    for (int k = 0; k < 16; ++k) mx = fmaxf(mx, s_t2[k][tid]);
    float se = 0.f, po = 0.f;
    for (int k = 0; k < 16; ++k) {
      float e = expf(s_t2[k][tid] - mx);
      se += e; po += e * s_ve[k][tid];
    }
    out[p*64 + tid] = po / se;
  }
}

// ---------------------------------------------------------------------------
extern "C" void kernel_launch(void* const* d_in, const int* in_sizes, int n_in,
                              void* d_out, int out_size, void* d_ws, size_t ws_size,
                              hipStream_t stream) {
  const float* x    = (const float*)d_in[0];
  const float* pos  = (const float*)d_in[1];
  const float* Wq   = (const float*)d_in[2];
  const float* Wk   = (const float*)d_in[3];
  const float* Wv   = (const float*)d_in[4];
  const float* p_w1 = (const float*)d_in[5];
  const float* p_b1 = (const float*)d_in[6];
  const float* p_g  = (const float*)d_in[7];
  const float* p_be = (const float*)d_in[8];
  const float* p_w2 = (const float*)d_in[9];
  const float* p_b2 = (const float*)d_in[10];
  const float* a_w1 = (const float*)d_in[11];
  const float* a_b1 = (const float*)d_in[12];
  const float* a_g  = (const float*)d_in[13];
  const float* a_be = (const float*)d_in[14];
  const float* a_w2 = (const float*)d_in[15];
  const float* a_b2 = (const float*)d_in[16];

  float* ws   = (float*)d_ws;
  float* qf   = ws;                    // 1048576 floats
  float* kf   = qf + 1048576;          // 1048576
  float* vf   = kf + 1048576;          // 1048576
  int*   idx  = (int*)(vf + 1048576);  // 262144 ints
  float* outp = (float*)d_out;

  hipLaunchKernelGGL(proj3_kernel, dim3(4096), dim3(256), 0, stream,
                     x, Wq, Wk, Wv, qf, kf, vf);
  hipLaunchKernelGGL(knn_blas_kernel, dim3(64, 4), dim3(64), 0, stream,
                     pos, idx);
  hipLaunchKernelGGL(fuse_dumb_kernel, dim3(16384), dim3(256), 0, stream,
                     pos, idx, qf, kf, vf,
                     p_w1, p_b1, p_g, p_be, p_w2, p_b2,
                     a_w1, a_b1, a_g, a_be, a_w2, a_b2, outp);
}

// Round 20
// 1024.311 us; speedup vs baseline: 1.2229x; 1.2229x over previous
//
#include <hip/hip_runtime.h>
#include <math.h>

#define NPTS 4096
#define KNN 16
#define LN_EPS 1e-5f

// ---------------------------------------------------------------------------
// FROZEN ORACLE (r17 PASS, r19 falsified stable-top16): np's neighbor sets
// are reproduced by the r17 SERIAL algorithm exactly:
//   d2: sq=(x2+y2)+z2 seq; dot=fma(z,z',fma(y,y',x*x')); d2=(sqn+sqm)-(2*dot)
//   selection: ascending-j scan, admission `d2 < ld[15]` (strict, d2-only),
//   16-deep displaced-carry insert chain comparing d2 ONLY.
// The chain's equal-d2 scramble is part of the oracle (np selection is
// unstable at ties; stable-(d2,j) top-16 provably fails — r19).
// DO NOT modify admission/insert semantics. r20 only adds ILP around it:
// AoS float4 LDS + 8x unrolled d2 (state mutates only on admission, in the
// same ascending-j order => bit-exact dynamics).
// ---------------------------------------------------------------------------

__global__ __launch_bounds__(256) void proj3_kernel(
    const float* __restrict__ x, const float* __restrict__ Wq,
    const float* __restrict__ Wk, const float* __restrict__ Wv,
    float* __restrict__ qf, float* __restrict__ kf, float* __restrict__ vf) {
  int g = blockIdx.x * 256 + threadIdx.x;
  int r = g >> 6, c = g & 63;
  float sq = 0.f, sk = 0.f, sv = 0.f;
  for (int i = 0; i < 64; ++i) {
    float xv = x[r*64 + i];
    sq += xv * Wq[i*64 + c];
    sk += xv * Wk[i*64 + c];
    sv += xv * Wv[i*64 + c];
  }
  qf[g] = sq; kf[g] = sk; vf[g] = sv;
}

// ---------------------------------------------------------------------------
// KNN: r17 serial dynamics, ILP-optimized. One thread per query; 64-thr
// blocks, grid (64, B). All lanes scan the same j => LDS float4 broadcast
// (conflict-free). 8x unroll: 8 independent loads + 8 independent d2 chains,
// then per-j admission in ascending order with the EXACT r17 chain.
// ---------------------------------------------------------------------------
__global__ __launch_bounds__(64) void knn_serial_ilp_kernel(
    const float* __restrict__ pos, int* __restrict__ idx_out) {
  __shared__ __align__(16) float4 s_p[NPTS];   // (x, y, z, sq) — 64 KB
  int tid = threadIdx.x, b = blockIdx.y;
  const float* pb = pos + b*NPTS*3;
  for (int j = tid; j < NPTS; j += 64) {
    float px = pb[j*3+0], py = pb[j*3+1], pz = pb[j*3+2];
    float sq = __fadd_rn(__fadd_rn(__fmul_rn(px,px), __fmul_rn(py,py)),
                         __fmul_rn(pz,pz));
    s_p[j] = make_float4(px, py, pz, sq);
  }
  __syncthreads();
  int n = blockIdx.x * 64 + tid;
  float4 qp = s_p[n];
  float qx = qp.x, qy = qp.y, qz = qp.z, sqn = qp.w;
  float ld[16]; int lj[16];
#pragma unroll
  for (int u = 0; u < 16; ++u) { ld[u] = INFINITY; lj[u] = 0x7fffffff; }
  for (int s = 0; s < NPTS; s += 8) {
    float4 p[8];
#pragma unroll
    for (int u = 0; u < 8; ++u) p[u] = s_p[s + u];
    float d2v[8];
#pragma unroll
    for (int u = 0; u < 8; ++u) {
      // V1 arithmetic, verbatim (BLAS FMA-chain dot, unfused combine)
      float acc = __fmul_rn(qx, p[u].x);
      acc = __fmaf_rn(qy, p[u].y, acc);
      acc = __fmaf_rn(qz, p[u].z, acc);
      d2v[u] = __fsub_rn(__fadd_rn(sqn, p[u].w), __fmul_rn(2.0f, acc));
    }
#pragma unroll
    for (int u = 0; u < 8; ++u) {
      float d2 = d2v[u];
      if (d2 < ld[15]) {                 // r17 admission: strict, d2-only
        float dd = d2; int jj = s + u;
#pragma unroll
        for (int v = 0; v < 16; ++v) {   // r17 chain: d2-only compare
          bool sw = dd < ld[v];
          float nd = sw ? dd : ld[v]; float td = sw ? ld[v] : dd;
          int   nj = sw ? jj : lj[v]; int   tj = sw ? lj[v] : jj;
          ld[v] = nd; lj[v] = nj; dd = td; jj = tj;
        }
      }
    }
  }
  int* outp = idx_out + (b*NPTS + n)*KNN;
#pragma unroll
  for (int u = 0; u < 16; ++u) outp[u] = b*NPTS + lj[u];   // GLOBAL row index
}

// ---------------------------------------------------------------------------
// Fused layer: r5 structure (known-good), + LDS staging of a_w1/a_w2/p_w2
// (identical accumulation order => bit-identical output), t2 aliased onto
// s_win storage. ~52 KB LDS => 3 blocks/CU.
// ---------------------------------------------------------------------------
__global__ __launch_bounds__(256) void fuse_kernel(
    const float* __restrict__ pos, const int* __restrict__ idx,
    const float* __restrict__ qf, const float* __restrict__ kf,
    const float* __restrict__ vf,
    const float* __restrict__ p_w1, const float* __restrict__ p_b1,
    const float* __restrict__ p_g, const float* __restrict__ p_be,
    const float* __restrict__ p_w2, const float* __restrict__ p_b2,
    const float* __restrict__ a_w1, const float* __restrict__ a_b1,
    const float* __restrict__ a_g, const float* __restrict__ a_be,
    const float* __restrict__ a_w2, const float* __restrict__ a_b2,
    float* __restrict__ out) {
  __shared__ int   s_j[16];
  __shared__ float s_h[16][12];
  __shared__ float s_win[16][64];     // reused as t2 after step 3
  __shared__ float s_ve[16][64];
  __shared__ float s_ai[16][64];
  __shared__ float s_act[16][64];
  __shared__ float s_m[16], s_rs[16];
  __shared__ float s_w1[4096];        // a_w1 [i][c]
  __shared__ float s_w2[4096];        // a_w2 [i][c]
  __shared__ float s_pw2[768];        // p_w2 [h][c]

  int tid = threadIdx.x;
  int p = blockIdx.x;

  for (int e = tid; e < 4096; e += 256) { s_w1[e] = a_w1[e]; s_w2[e] = a_w2[e]; }
  for (int e = tid; e < 768; e += 256) s_pw2[e] = p_w2[e];

  if (tid < 16) {
    int j = idx[p*KNN + tid];
    s_j[tid] = j;
    float rx = pos[p*3+0] - pos[j*3+0];
    float ry = pos[p*3+1] - pos[j*3+1];
    float rz = pos[p*3+2] - pos[j*3+2];
    float hv[12];
    float mean = 0.f;
#pragma unroll
    for (int h = 0; h < 12; ++h) {
      float v = rx*p_w1[h] + ry*p_w1[12+h] + rz*p_w1[24+h] + p_b1[h];
      hv[h] = v; mean += v;
    }
    mean *= (1.0f/12.0f);
    float var = 0.f;
#pragma unroll
    for (int h = 0; h < 12; ++h) { float d = hv[h] - mean; var += d*d; }
    var *= (1.0f/12.0f);
    float rs = rsqrtf(var + LN_EPS);
#pragma unroll
    for (int h = 0; h < 12; ++h) {
      float a = (hv[h] - mean)*rs*p_g[h] + p_be[h];
      s_h[tid][h] = fmaxf(a, 0.f);
    }
  }
  __syncthreads();

  int c = tid & 63, kq = tid >> 6;

  {
    float qv = qf[p*64 + c];
#pragma unroll
    for (int it = 0; it < 4; ++it) {
      int k = it*4 + kq;
      int j = s_j[k];
      float pe = p_b2[c];
#pragma unroll
      for (int h = 0; h < 12; ++h) pe += s_h[k][h] * s_pw2[h*64 + c];
      s_win[k][c] = qv - kf[j*64 + c] + pe;
      s_ve[k][c]  = vf[j*64 + c] + pe;
    }
  }
  __syncthreads();

#pragma unroll
  for (int it = 0; it < 4; ++it) {
    int k = it*4 + kq;
    float s = a_b1[c];
    for (int i = 0; i < 64; ++i) s += s_win[k][i] * s_w1[i*64 + c];
    s_ai[k][c] = s;
  }
  __syncthreads();

  if (tid < 16) {
    float m = 0.f;
    for (int c2 = 0; c2 < 64; ++c2) m += s_ai[tid][c2];
    m *= (1.0f/64.0f);
    float v = 0.f;
    for (int c2 = 0; c2 < 64; ++c2) { float d = s_ai[tid][c2] - m; v += d*d; }
    v *= (1.0f/64.0f);
    s_m[tid] = m; s_rs[tid] = rsqrtf(v + LN_EPS);
  }
  __syncthreads();
#pragma unroll
  for (int it = 0; it < 4; ++it) {
    int k = it*4 + kq;
    s_act[k][c] = fmaxf((s_ai[k][c] - s_m[k])*s_rs[k]*a_g[c] + a_be[c], 0.f);
  }
  __syncthreads();

  // t2 into s_win storage (s_win dead after step 3)
#pragma unroll
  for (int it = 0; it < 4; ++it) {
    int k = it*4 + kq;
    float s = a_b2[c];
    for (int i = 0; i < 64; ++i) s += s_act[k][i] * s_w2[i*64 + c];
    s_win[k][c] = s;
  }
  __syncthreads();

  if (tid < 64) {
    float mx = -INFINITY;
    for (int k = 0; k < 16; ++k) mx = fmaxf(mx, s_win[k][tid]);
    float se = 0.f, po = 0.f;
    for (int k = 0; k < 16; ++k) {
      float e = expf(s_win[k][tid] - mx);
      se += e; po += e * s_ve[k][tid];
    }
    out[p*64 + tid] = po / se;
  }
}

// ---------------------------------------------------------------------------
extern "C" void kernel_launch(void* const* d_in, const int* in_sizes, int n_in,
                              void* d_out, int out_size, void* d_ws, size_t ws_size,
                              hipStream_t stream) {
  const float* x    = (const float*)d_in[0];
  const float* pos  = (const float*)d_in[1];
  const float* Wq   = (const float*)d_in[2];
  const float* Wk   = (const float*)d_in[3];
  const float* Wv   = (const float*)d_in[4];
  const float* p_w1 = (const float*)d_in[5];
  const float* p_b1 = (const float*)d_in[6];
  const float* p_g  = (const float*)d_in[7];
  const float* p_be = (const float*)d_in[8];
  const float* p_w2 = (const float*)d_in[9];
  const float* p_b2 = (const float*)d_in[10];
  const float* a_w1 = (const float*)d_in[11];
  const float* a_b1 = (const float*)d_in[12];
  const float* a_g  = (const float*)d_in[13];
  const float* a_be = (const float*)d_in[14];
  const float* a_w2 = (const float*)d_in[15];
  const float* a_b2 = (const float*)d_in[16];

  float* ws   = (float*)d_ws;
  float* qf   = ws;                    // 1048576 floats
  float* kf   = qf + 1048576;          // 1048576
  float* vf   = kf + 1048576;          // 1048576
  int*   idx  = (int*)(vf + 1048576);  // 262144 ints
  float* outp = (float*)d_out;

  hipLaunchKernelGGL(proj3_kernel, dim3(4096), dim3(256), 0, stream,
                     x, Wq, Wk, Wv, qf, kf, vf);
  hipLaunchKernelGGL(knn_serial_ilp_kernel, dim3(64, 4), dim3(64), 0, stream,
                     pos, idx);
  hipLaunchKernelGGL(fuse_kernel, dim3(16384), dim3(256), 0, stream,
                     pos, idx, qf, kf, vf,
                     p_w1, p_b1, p_g, p_be, p_w2, p_b2,
                     a_w1, a_b1, a_g, a_be, a_w2, a_b2, outp);
}